// Round 2
// baseline (1029.623 us; speedup 1.0000x reference)
//
#include <hip/hip_runtime.h>

constexpr int   N       = 8192;
constexpr float INV_REG = 10.0f;    // 1/REG, REG = 0.1
constexpr float THRESH  = 1e-3f;
constexpr float EPSV    = 1e-8f;
constexpr int   MAX_IT  = 100;
constexpr int   NSLAB   = 64;       // row slabs for K^T u partials

// ---------------------------------------------------------------------------
// init: K = exp(-cost/REG) into d_out; u = 1/N; flag = 0
__global__ __launch_bounds__(256)
void k_init(const float* __restrict__ cost, float* __restrict__ K,
            float* __restrict__ u, int* __restrict__ flag)
{
    const int gtid = blockIdx.x * 256 + threadIdx.x;
    const int gsz  = gridDim.x * 256;
    const float4* c4 = (const float4*)cost;
    float4*       k4 = (float4*)K;
    const int tot4 = N * N / 4;
    for (int i = gtid; i < tot4; i += gsz) {
        float4 c = c4[i];
        float4 k;
        k.x = __expf(-INV_REG * c.x);
        k.y = __expf(-INV_REG * c.y);
        k.z = __expf(-INV_REG * c.z);
        k.w = __expf(-INV_REG * c.w);
        k4[i] = k;
    }
    if (gtid < N) u[gtid] = 1.0f / (float)N;
    if (gtid == 0) *flag = 0;
}

// ---------------------------------------------------------------------------
// colmv: partial[rs][j] = sum over rows r in slab rs of K[r][j]*u[r]
// grid = 1024 blocks (64 row-slabs x 16 col-slabs of 512 cols), 256 thr
__global__ __launch_bounds__(256)
void k_colmv(const float* __restrict__ K, const float* __restrict__ u,
             float* __restrict__ partial, const int* __restrict__ flag)
{
    if (*flag) return;
    __shared__ float  uh[128];
    __shared__ __align__(16) float4 accs[128];

    const int rs = blockIdx.x >> 4;      // 0..63
    const int cs = blockIdx.x & 15;      // 0..15
    const int r0 = rs * 128;
    const int c0 = cs * 512;
    const int l  = threadIdx.x & 127;    // float4 lane over 512 cols
    const int h  = threadIdx.x >> 7;     // row-half

    if (threadIdx.x < 128) uh[threadIdx.x] = u[r0 + threadIdx.x];
    __syncthreads();

    float4 acc = make_float4(0.f, 0.f, 0.f, 0.f);
    for (int r = h; r < 128; r += 2) {
        float4 k = ((const float4*)(K + (size_t)(r0 + r) * N))[(c0 >> 2) + l];
        float uu = uh[r];
        acc.x += k.x * uu;
        acc.y += k.y * uu;
        acc.z += k.z * uu;
        acc.w += k.w * uu;
    }
    if (h == 1) accs[l] = acc;
    __syncthreads();
    if (h == 0) {
        float4 o = accs[l];
        acc.x += o.x; acc.y += o.y; acc.z += o.z; acc.w += o.w;
        ((float4*)(partial + (size_t)rs * N + c0))[l] = acc;
    }
}

// ---------------------------------------------------------------------------
// v_j = b_j / (sum_s partial[s][j] + eps);  grid = 32 x 256
__global__ __launch_bounds__(256)
void k_v(const float* __restrict__ partial, const float* __restrict__ bv,
         float* __restrict__ v, const int* __restrict__ flag)
{
    if (*flag) return;
    const int j = blockIdx.x * 256 + threadIdx.x;
    float s = 0.f;
    for (int sl = 0; sl < NSLAB; ++sl) s += partial[(size_t)sl * N + j];
    v[j] = bv[j] / (s + EPSV);
}

// ---------------------------------------------------------------------------
// rowmv: u_i = a_i / (K[i,:] . v + eps); du2_i = (u_new - u_old)^2
// grid = 2048 blocks x 256 thr, one wave per row (4 rows per block)
__global__ __launch_bounds__(256)
void k_rowmv(const float* __restrict__ K, const float* __restrict__ av,
             const float* __restrict__ v, float* __restrict__ u,
             float* __restrict__ du2, const int* __restrict__ flag)
{
    if (*flag) return;
    __shared__ __align__(16) float vl[N];
    for (int j = threadIdx.x; j < N / 4; j += 256)
        ((float4*)vl)[j] = ((const float4*)v)[j];
    __syncthreads();

    const int w    = threadIdx.x >> 6;
    const int lane = threadIdx.x & 63;
    const int i    = blockIdx.x * 4 + w;
    const float4* krow = (const float4*)(K + (size_t)i * N);
    const float4* v4   = (const float4*)vl;

    float acc = 0.f;
    for (int c = lane; c < N / 4; c += 64) {
        float4 k  = krow[c];
        float4 vv = v4[c];
        acc += k.x * vv.x + k.y * vv.y + k.z * vv.z + k.w * vv.w;
    }
    for (int off = 32; off > 0; off >>= 1)
        acc += __shfl_down(acc, off, 64);
    if (lane == 0) {
        float un = av[i] / (acc + EPSV);
        float d  = un - u[i];
        du2[i] = d * d;
        u[i]   = un;
    }
}

// ---------------------------------------------------------------------------
// err gate: err = sqrt(sum du2); if err < THRESH -> flag = 1.  1 block x 256
__global__ __launch_bounds__(256)
void k_err(const float* __restrict__ du2, int* __restrict__ flag)
{
    if (*flag) return;
    __shared__ float r[4];
    float s = 0.f;
    for (int i = threadIdx.x; i < N; i += 256) s += du2[i];
    for (int off = 32; off > 0; off >>= 1)
        s += __shfl_down(s, off, 64);
    if ((threadIdx.x & 63) == 0) r[threadIdx.x >> 6] = s;
    __syncthreads();
    if (threadIdx.x == 0) {
        float e = sqrtf(r[0] + r[1] + r[2] + r[3]);
        if (e < THRESH) *flag = 1;
    }
}

// ---------------------------------------------------------------------------
// final: out[i][j] = u_i * K[i][j] * v_j, in place.  grid = 2048 x 256
__global__ __launch_bounds__(256)
void k_final(float* __restrict__ K, const float* __restrict__ u,
             const float* __restrict__ v)
{
    __shared__ __align__(16) float vl[N];
    for (int j = threadIdx.x; j < N / 4; j += 256)
        ((float4*)vl)[j] = ((const float4*)v)[j];
    __syncthreads();

    const int w    = threadIdx.x >> 6;
    const int lane = threadIdx.x & 63;
    const int i    = blockIdx.x * 4 + w;
    const float ui = u[i];
    float4* krow = (float4*)(K + (size_t)i * N);
    const float4* v4 = (const float4*)vl;
    for (int c = lane; c < N / 4; c += 64) {
        float4 k  = krow[c];
        float4 vv = v4[c];
        k.x *= ui * vv.x;
        k.y *= ui * vv.y;
        k.z *= ui * vv.z;
        k.w *= ui * vv.w;
        krow[c] = k;
    }
}

// ---------------------------------------------------------------------------
extern "C" void kernel_launch(void* const* d_in, const int* in_sizes, int n_in,
                              void* d_out, int out_size, void* d_ws, size_t ws_size,
                              hipStream_t stream)
{
    const float* cost = (const float*)d_in[0];
    const float* av   = (const float*)d_in[1];
    const float* bv   = (const float*)d_in[2];
    float* K = (float*)d_out;

    // ws layout: flag (int, 64B-aligned slot), u[N], v[N], du2[N], partial[64*N]
    int*   flag    = (int*)d_ws;
    float* u       = (float*)d_ws + 16;
    float* v       = u + N;
    float* du2     = v + N;
    float* partial = du2 + N;

    k_init<<<2048, 256, 0, stream>>>(cost, K, u, flag);
    for (int it = 0; it < MAX_IT; ++it) {
        k_colmv<<<1024, 256, 0, stream>>>(K, u, partial, flag);
        k_v    <<<  32, 256, 0, stream>>>(partial, bv, v, flag);
        k_rowmv<<<2048, 256, 0, stream>>>(K, av, v, u, du2, flag);
        k_err  <<<   1, 256, 0, stream>>>(du2, flag);
    }
    k_final<<<2048, 256, 0, stream>>>(K, u, v);
}

// Round 3
// 929.300 us; speedup vs baseline: 1.1080x; 1.1080x over previous
//
#include <hip/hip_runtime.h>
#include <hip/hip_cooperative_groups.h>

namespace cg = cooperative_groups;

constexpr int   N       = 8192;
constexpr float INV_REG = 10.0f;    // 1/REG, REG = 0.1
constexpr float THRESH  = 1e-3f;
constexpr float EPSV    = 1e-8f;
constexpr int   MAX_IT  = 100;

constexpr int   NBLK    = 512;      // 2 blocks/CU guaranteed (33KB LDS, <=256 VGPR)
constexpr int   NTHR    = 256;
constexpr int   NSLAB_C = 32;       // row slabs in cooperative colmv (256 rows each)

// ===========================================================================
// Cooperative mega-kernel: init + full Sinkhorn loop + final rescale.
// ws layout (floats): partial[32][N] (1MB), u[N], v[N], du2[N]
// ===========================================================================
__global__ __launch_bounds__(NTHR, 2)
void sinkhorn_mega(const float* __restrict__ cost,
                   const float* __restrict__ av,
                   const float* __restrict__ bv,
                   float* __restrict__ K,      // d_out
                   float* __restrict__ ws)
{
    cg::grid_group grid = cg::this_grid();

    float* partial = ws;
    float* u       = ws + NSLAB_C * N;
    float* v       = u + N;
    float* du2     = v + N;

    const int tid  = threadIdx.x;
    const int bid  = blockIdx.x;
    const int gtid = bid * NTHR + tid;
    const int gsz  = NBLK * NTHR;

    __shared__ __align__(16) float v_lds[N];   // 32 KB
    __shared__ float u_lds[256];
    __shared__ float red[4];
    __shared__ float err_sh;

    // ---------------- init: K = exp(-cost/REG); u = 1/N ----------------
    {
        const float4* c4 = (const float4*)cost;
        float4*       k4 = (float4*)K;
        const int tot4 = N * N / 4;
        for (int i = gtid; i < tot4; i += gsz) {
            float4 c = c4[i];
            float4 k;
            k.x = __expf(-INV_REG * c.x);
            k.y = __expf(-INV_REG * c.y);
            k.z = __expf(-INV_REG * c.z);
            k.w = __expf(-INV_REG * c.w);
            k4[i] = k;
        }
        if (gtid < N) u[gtid] = 1.0f / (float)N;
    }
    grid.sync();

    int iter = 0;
    while (true) {
        // ---- A: partial[rs][j] = sum_{r in slab rs} K[r][j] * u[r] ----
        {
            const int rs = bid >> 4;          // 0..31, 256 rows each
            const int cs = bid & 15;          // 0..15, 512 cols each
            const int r0 = rs * 256;
            const int c0 = cs * 512;
            const int l  = tid & 127;         // float4 lane over 512 cols
            const int h  = tid >> 7;          // row half

            u_lds[tid] = u[r0 + tid];
            __syncthreads();

            float4 acc = make_float4(0.f, 0.f, 0.f, 0.f);
            for (int r = h; r < 256; r += 2) {
                float4 k = ((const float4*)(K + (size_t)(r0 + r) * N))[(c0 >> 2) + l];
                float uu = u_lds[r];
                acc.x += k.x * uu;
                acc.y += k.y * uu;
                acc.z += k.z * uu;
                acc.w += k.w * uu;
            }
            // combine the two halves via LDS (reuse v_lds scratch)
            if (h == 1) ((float4*)v_lds)[l] = acc;
            __syncthreads();
            if (h == 0) {
                float4 o = ((float4*)v_lds)[l];
                acc.x += o.x; acc.y += o.y; acc.z += o.z; acc.w += o.w;
                ((float4*)(partial + (size_t)rs * N + c0))[l] = acc;
            }
            __syncthreads();   // v_lds scratch done before anyone re-stages it
        }
        grid.sync();

        // ---- A2: v[j] = b[j] / (sum_s partial[s][j] + eps) ----
        if (gtid < N) {
            float s = 0.f;
            for (int sl = 0; sl < NSLAB_C; ++sl) s += partial[(size_t)sl * N + gtid];
            v[gtid] = bv[gtid] / (s + EPSV);
        }
        grid.sync();

        // ---- B: u[i] = a[i] / (K[i,:].v + eps); du2 ----
        {
            for (int j = tid; j < N / 4; j += NTHR)
                ((float4*)v_lds)[j] = ((const float4*)v)[j];
            __syncthreads();

            const int w    = tid >> 6;
            const int lane = tid & 63;
            const float4* v4 = (const float4*)v_lds;
            for (int rr = 0; rr < 4; ++rr) {
                const int i = bid * 16 + w * 4 + rr;
                const float4* krow = (const float4*)(K + (size_t)i * N);
                float acc = 0.f;
                for (int c = lane; c < N / 4; c += 64) {
                    float4 k  = krow[c];
                    float4 vv = v4[c];
                    acc += k.x * vv.x + k.y * vv.y + k.z * vv.z + k.w * vv.w;
                }
                for (int off = 32; off > 0; off >>= 1)
                    acc += __shfl_down(acc, off, 64);
                if (lane == 0) {
                    float un = av[i] / (acc + EPSV);
                    float d  = un - u[i];
                    du2[i] = d * d;
                    u[i]   = un;
                }
            }
        }
        grid.sync();

        // ---- C: every block redundantly reduces du2 (identical fp order) ----
        {
            float s = 0.f;
            for (int i = tid; i < N; i += NTHR) s += du2[i];
            for (int off = 32; off > 0; off >>= 1)
                s += __shfl_down(s, off, 64);
            if ((tid & 63) == 0) red[tid >> 6] = s;
            __syncthreads();
            if (tid == 0) err_sh = sqrtf(red[0] + red[1] + red[2] + red[3]);
            __syncthreads();
            float err = err_sh;
            ++iter;
            if (iter >= MAX_IT || err < THRESH) break;
        }
        // no grid.sync needed here: next phase A reads u (synced after B) and
        // writes partial (all readers passed the post-A2 sync).
    }

    // ---- final: K[i][j] *= u[i]*v[j], in place; v_lds still holds v ----
    {
        const int w    = tid >> 6;
        const int lane = tid & 63;
        const float4* v4 = (const float4*)v_lds;
        for (int rr = 0; rr < 4; ++rr) {
            const int i = bid * 16 + w * 4 + rr;
            const float ui = u[i];
            float4* krow = (float4*)(K + (size_t)i * N);
            for (int c = lane; c < N / 4; c += 64) {
                float4 k  = krow[c];
                float4 vv = v4[c];
                k.x *= ui * vv.x;
                k.y *= ui * vv.y;
                k.z *= ui * vv.z;
                k.w *= ui * vv.w;
                krow[c] = k;
            }
        }
    }
}

// ===========================================================================
// Fallback path (round-2 proven kernels) — used only if the cooperative
// launch is rejected by the runtime.
// ===========================================================================
constexpr int NSLAB_F = 64;

__global__ __launch_bounds__(256)
void k_init(const float* __restrict__ cost, float* __restrict__ K,
            float* __restrict__ u, int* __restrict__ flag)
{
    const int gtid = blockIdx.x * 256 + threadIdx.x;
    const int gsz  = gridDim.x * 256;
    const float4* c4 = (const float4*)cost;
    float4*       k4 = (float4*)K;
    const int tot4 = N * N / 4;
    for (int i = gtid; i < tot4; i += gsz) {
        float4 c = c4[i];
        float4 k;
        k.x = __expf(-INV_REG * c.x);
        k.y = __expf(-INV_REG * c.y);
        k.z = __expf(-INV_REG * c.z);
        k.w = __expf(-INV_REG * c.w);
        k4[i] = k;
    }
    if (gtid < N) u[gtid] = 1.0f / (float)N;
    if (gtid == 0) *flag = 0;
}

__global__ __launch_bounds__(256)
void k_colmv(const float* __restrict__ K, const float* __restrict__ u,
             float* __restrict__ partial, const int* __restrict__ flag)
{
    if (*flag) return;
    __shared__ float  uh[128];
    __shared__ __align__(16) float4 accs[128];

    const int rs = blockIdx.x >> 4;
    const int cs = blockIdx.x & 15;
    const int r0 = rs * 128;
    const int c0 = cs * 512;
    const int l  = threadIdx.x & 127;
    const int h  = threadIdx.x >> 7;

    if (threadIdx.x < 128) uh[threadIdx.x] = u[r0 + threadIdx.x];
    __syncthreads();

    float4 acc = make_float4(0.f, 0.f, 0.f, 0.f);
    for (int r = h; r < 128; r += 2) {
        float4 k = ((const float4*)(K + (size_t)(r0 + r) * N))[(c0 >> 2) + l];
        float uu = uh[r];
        acc.x += k.x * uu;
        acc.y += k.y * uu;
        acc.z += k.z * uu;
        acc.w += k.w * uu;
    }
    if (h == 1) accs[l] = acc;
    __syncthreads();
    if (h == 0) {
        float4 o = accs[l];
        acc.x += o.x; acc.y += o.y; acc.z += o.z; acc.w += o.w;
        ((float4*)(partial + (size_t)rs * N + c0))[l] = acc;
    }
}

__global__ __launch_bounds__(256)
void k_v(const float* __restrict__ partial, const float* __restrict__ bv,
         float* __restrict__ v, const int* __restrict__ flag)
{
    if (*flag) return;
    const int j = blockIdx.x * 256 + threadIdx.x;
    float s = 0.f;
    for (int sl = 0; sl < NSLAB_F; ++sl) s += partial[(size_t)sl * N + j];
    v[j] = bv[j] / (s + EPSV);
}

__global__ __launch_bounds__(256)
void k_rowmv(const float* __restrict__ K, const float* __restrict__ av,
             const float* __restrict__ v, float* __restrict__ u,
             float* __restrict__ du2, const int* __restrict__ flag)
{
    if (*flag) return;
    __shared__ __align__(16) float vl[N];
    for (int j = threadIdx.x; j < N / 4; j += 256)
        ((float4*)vl)[j] = ((const float4*)v)[j];
    __syncthreads();

    const int w    = threadIdx.x >> 6;
    const int lane = threadIdx.x & 63;
    const int i    = blockIdx.x * 4 + w;
    const float4* krow = (const float4*)(K + (size_t)i * N);
    const float4* v4   = (const float4*)vl;

    float acc = 0.f;
    for (int c = lane; c < N / 4; c += 64) {
        float4 k  = krow[c];
        float4 vv = v4[c];
        acc += k.x * vv.x + k.y * vv.y + k.z * vv.z + k.w * vv.w;
    }
    for (int off = 32; off > 0; off >>= 1)
        acc += __shfl_down(acc, off, 64);
    if (lane == 0) {
        float un = av[i] / (acc + EPSV);
        float d  = un - u[i];
        du2[i] = d * d;
        u[i]   = un;
    }
}

__global__ __launch_bounds__(256)
void k_err(const float* __restrict__ du2, int* __restrict__ flag)
{
    if (*flag) return;
    __shared__ float r[4];
    float s = 0.f;
    for (int i = threadIdx.x; i < N; i += 256) s += du2[i];
    for (int off = 32; off > 0; off >>= 1)
        s += __shfl_down(s, off, 64);
    if ((threadIdx.x & 63) == 0) r[threadIdx.x >> 6] = s;
    __syncthreads();
    if (threadIdx.x == 0) {
        float e = sqrtf(r[0] + r[1] + r[2] + r[3]);
        if (e < THRESH) *flag = 1;
    }
}

__global__ __launch_bounds__(256)
void k_final(float* __restrict__ K, const float* __restrict__ u,
             const float* __restrict__ v)
{
    __shared__ __align__(16) float vl[N];
    for (int j = threadIdx.x; j < N / 4; j += 256)
        ((float4*)vl)[j] = ((const float4*)v)[j];
    __syncthreads();

    const int w    = threadIdx.x >> 6;
    const int lane = threadIdx.x & 63;
    const int i    = blockIdx.x * 4 + w;
    const float ui = u[i];
    float4* krow = (float4*)(K + (size_t)i * N);
    const float4* v4 = (const float4*)vl;
    for (int c = lane; c < N / 4; c += 64) {
        float4 k  = krow[c];
        float4 vv = v4[c];
        k.x *= ui * vv.x;
        k.y *= ui * vv.y;
        k.z *= ui * vv.z;
        k.w *= ui * vv.w;
        krow[c] = k;
    }
}

// ===========================================================================
extern "C" void kernel_launch(void* const* d_in, const int* in_sizes, int n_in,
                              void* d_out, int out_size, void* d_ws, size_t ws_size,
                              hipStream_t stream)
{
    const float* cost = (const float*)d_in[0];
    const float* av   = (const float*)d_in[1];
    const float* bv   = (const float*)d_in[2];
    float* K  = (float*)d_out;
    float* ws = (float*)d_ws;

    // Try the single cooperative mega-kernel first.
    {
        void* args[] = { (void*)&cost, (void*)&av, (void*)&bv, (void*)&K, (void*)&ws };
        hipError_t rc = hipLaunchCooperativeKernel((const void*)sinkhorn_mega,
                                                   dim3(NBLK), dim3(NTHR),
                                                   args, 0, stream);
        if (rc == hipSuccess) return;
    }

    // Fallback: proven round-2 multi-kernel path.
    // ws layout: flag (int, in a 64B slot), u[N], v[N], du2[N], partial[64*N]
    int*   flag    = (int*)d_ws;
    float* u       = (float*)d_ws + 16;
    float* v       = u + N;
    float* du2     = v + N;
    float* partial = du2 + N;

    k_init<<<2048, 256, 0, stream>>>(cost, K, u, flag);
    for (int it = 0; it < MAX_IT; ++it) {
        k_colmv<<<1024, 256, 0, stream>>>(K, u, partial, flag);
        k_v    <<<  32, 256, 0, stream>>>(partial, bv, v, flag);
        k_rowmv<<<2048, 256, 0, stream>>>(K, av, v, u, du2, flag);
        k_err  <<<   1, 256, 0, stream>>>(du2, flag);
    }
    k_final<<<2048, 256, 0, stream>>>(K, u, v);
}

// Round 4
// 803.804 us; speedup vs baseline: 1.2809x; 1.1561x over previous
//
#include <hip/hip_runtime.h>
#include <hip/hip_cooperative_groups.h>

namespace cg = cooperative_groups;

constexpr int   N       = 8192;
constexpr float INV_REG = 10.0f;    // 1/REG, REG = 0.1
constexpr float THRESH  = 1e-3f;
constexpr float EPSV    = 1e-8f;
constexpr int   MAX_IT  = 100;
constexpr int   NTHR    = 256;
constexpr int   MAXSLAB = 64;       // ws reservation for partial[slab][N]

// ===========================================================================
// Cooperative mega-kernel (grid-size agnostic: works for 512 or 1024 blocks).
// ws layout (floats): partial[MAXSLAB][N] (2MB), u[N], v[N], du2[N]
// ===========================================================================
__global__ __launch_bounds__(NTHR, 4)
void sinkhorn_mega(const float* __restrict__ cost,
                   const float* __restrict__ av,
                   const float* __restrict__ bv,
                   float* __restrict__ K,      // d_out
                   float* __restrict__ ws)
{
    cg::grid_group grid = cg::this_grid();

    float* partial = ws;
    float* u       = ws + (size_t)MAXSLAB * N;
    float* v       = u + N;
    float* du2     = v + N;

    const int tid  = threadIdx.x;
    const int bid  = blockIdx.x;
    const int nblk = gridDim.x;
    const int gtid = bid * NTHR + tid;
    const int gsz  = nblk * NTHR;

    const int RS        = nblk >> 4;       // row slabs (16 col-slabs fixed)
    const int rows_slab = N / RS;          // 128 @1024 blk, 256 @512 blk
    const int rpb       = N / nblk;        // rows per block in row-matvec
    const int per_wave  = rpb >> 2;        // rows per wave

    __shared__ __align__(16) float v_lds[N];   // 32 KB
    __shared__ float u_lds[256];
    __shared__ float red[4];
    __shared__ float err_sh;

    // ---------------- init: K = exp(-cost/REG); u = 1/N ----------------
    {
        const float4* c4 = (const float4*)cost;
        float4*       k4 = (float4*)K;
        const int tot4 = N * N / 4;
        #pragma unroll 2
        for (int i = gtid; i < tot4; i += gsz) {
            float4 c = c4[i];
            float4 k;
            k.x = __expf(-INV_REG * c.x);
            k.y = __expf(-INV_REG * c.y);
            k.z = __expf(-INV_REG * c.z);
            k.w = __expf(-INV_REG * c.w);
            k4[i] = k;
        }
        if (gtid < N) u[gtid] = 1.0f / (float)N;
    }
    grid.sync();

    int iter = 0;
    while (true) {
        // ---- A: partial[rs][j] = sum_{r in slab rs} K[r][j] * u[r] ----
        {
            const int rs = bid >> 4;
            const int cs = bid & 15;
            const int r0 = rs * rows_slab;
            const int c0 = cs * 512;
            const int l  = tid & 127;     // float4 lane over 512 cols
            const int h  = tid >> 7;      // row half

            for (int r = tid; r < rows_slab; r += NTHR) u_lds[r] = u[r0 + r];
            __syncthreads();

            float4 acc = make_float4(0.f, 0.f, 0.f, 0.f);
            #pragma unroll 4
            for (int r = h; r < rows_slab; r += 2) {
                float4 k = ((const float4*)(K + (size_t)(r0 + r) * N))[(c0 >> 2) + l];
                float uu = u_lds[r];
                acc.x += k.x * uu;
                acc.y += k.y * uu;
                acc.z += k.z * uu;
                acc.w += k.w * uu;
            }
            if (h == 1) ((float4*)v_lds)[l] = acc;
            __syncthreads();
            if (h == 0) {
                float4 o = ((float4*)v_lds)[l];
                acc.x += o.x; acc.y += o.y; acc.z += o.z; acc.w += o.w;
                ((float4*)(partial + (size_t)rs * N + c0))[l] = acc;
            }
            __syncthreads();   // v_lds scratch free before next use
        }
        grid.sync();

        // ---- A2: v[j] = b[j] / (sum_s partial[s][j] + eps) ----
        if (gtid < N) {
            float s = 0.f;
            for (int sl = 0; sl < RS; ++sl) s += partial[(size_t)sl * N + gtid];
            v[gtid] = bv[gtid] / (s + EPSV);
        }
        grid.sync();

        // ---- B: u[i] = a[i] / (K[i,:].v + eps); du2 ----
        {
            for (int j = tid; j < N / 4; j += NTHR)
                ((float4*)v_lds)[j] = ((const float4*)v)[j];
            __syncthreads();

            const int w    = tid >> 6;
            const int lane = tid & 63;
            const float4* v4 = (const float4*)v_lds;
            for (int rr = 0; rr < per_wave; ++rr) {
                const int i = bid * rpb + w * per_wave + rr;
                const float4* krow = (const float4*)(K + (size_t)i * N);
                float acc = 0.f;
                #pragma unroll 4
                for (int c = lane; c < N / 4; c += 64) {
                    float4 k  = krow[c];
                    float4 vv = v4[c];
                    acc += k.x * vv.x + k.y * vv.y + k.z * vv.z + k.w * vv.w;
                }
                for (int off = 32; off > 0; off >>= 1)
                    acc += __shfl_down(acc, off, 64);
                if (lane == 0) {
                    float un = av[i] / (acc + EPSV);
                    float d  = un - u[i];
                    du2[i] = d * d;
                    u[i]   = un;
                }
            }
        }
        grid.sync();

        // ---- C: every block redundantly reduces du2 (identical fp order) ----
        {
            float s = 0.f;
            for (int i = tid; i < N; i += NTHR) s += du2[i];
            for (int off = 32; off > 0; off >>= 1)
                s += __shfl_down(s, off, 64);
            if ((tid & 63) == 0) red[tid >> 6] = s;
            __syncthreads();
            if (tid == 0) err_sh = sqrtf(red[0] + red[1] + red[2] + red[3]);
            __syncthreads();
            float err = err_sh;
            ++iter;
            if (iter >= MAX_IT || err < THRESH) break;
        }
        // next A reads u (grid-synced after B) and rewrites partial (all
        // readers passed the post-A2 sync) -> no extra grid.sync needed.
    }

    // ---- final: K[i][j] *= u[i]*v[j]; v_lds still holds v from phase B ----
    {
        const int w    = tid >> 6;
        const int lane = tid & 63;
        const float4* v4 = (const float4*)v_lds;
        for (int rr = 0; rr < per_wave; ++rr) {
            const int i = bid * rpb + w * per_wave + rr;
            const float ui = u[i];
            float4* krow = (float4*)(K + (size_t)i * N);
            #pragma unroll 4
            for (int c = lane; c < N / 4; c += 64) {
                float4 k  = krow[c];
                float4 vv = v4[c];
                k.x *= ui * vv.x;
                k.y *= ui * vv.y;
                k.z *= ui * vv.z;
                k.w *= ui * vv.w;
                krow[c] = k;
            }
        }
    }
}

// ===========================================================================
// Fallback path (round-2 proven multi-kernel) — only if coop launch impossible
// ===========================================================================
constexpr int NSLAB_F = 64;

__global__ __launch_bounds__(256)
void k_init(const float* __restrict__ cost, float* __restrict__ K,
            float* __restrict__ u, int* __restrict__ flag)
{
    const int gtid = blockIdx.x * 256 + threadIdx.x;
    const int gsz  = gridDim.x * 256;
    const float4* c4 = (const float4*)cost;
    float4*       k4 = (float4*)K;
    const int tot4 = N * N / 4;
    for (int i = gtid; i < tot4; i += gsz) {
        float4 c = c4[i];
        float4 k;
        k.x = __expf(-INV_REG * c.x);
        k.y = __expf(-INV_REG * c.y);
        k.z = __expf(-INV_REG * c.z);
        k.w = __expf(-INV_REG * c.w);
        k4[i] = k;
    }
    if (gtid < N) u[gtid] = 1.0f / (float)N;
    if (gtid == 0) *flag = 0;
}

__global__ __launch_bounds__(256)
void k_colmv(const float* __restrict__ K, const float* __restrict__ u,
             float* __restrict__ partial, const int* __restrict__ flag)
{
    if (*flag) return;
    __shared__ float  uh[128];
    __shared__ __align__(16) float4 accs[128];

    const int rs = blockIdx.x >> 4;
    const int cs = blockIdx.x & 15;
    const int r0 = rs * 128;
    const int c0 = cs * 512;
    const int l  = threadIdx.x & 127;
    const int h  = threadIdx.x >> 7;

    if (threadIdx.x < 128) uh[threadIdx.x] = u[r0 + threadIdx.x];
    __syncthreads();

    float4 acc = make_float4(0.f, 0.f, 0.f, 0.f);
    for (int r = h; r < 128; r += 2) {
        float4 k = ((const float4*)(K + (size_t)(r0 + r) * N))[(c0 >> 2) + l];
        float uu = uh[r];
        acc.x += k.x * uu;
        acc.y += k.y * uu;
        acc.z += k.z * uu;
        acc.w += k.w * uu;
    }
    if (h == 1) accs[l] = acc;
    __syncthreads();
    if (h == 0) {
        float4 o = accs[l];
        acc.x += o.x; acc.y += o.y; acc.z += o.z; acc.w += o.w;
        ((float4*)(partial + (size_t)rs * N + c0))[l] = acc;
    }
}

__global__ __launch_bounds__(256)
void k_v(const float* __restrict__ partial, const float* __restrict__ bv,
         float* __restrict__ v, const int* __restrict__ flag)
{
    if (*flag) return;
    const int j = blockIdx.x * 256 + threadIdx.x;
    float s = 0.f;
    for (int sl = 0; sl < NSLAB_F; ++sl) s += partial[(size_t)sl * N + j];
    v[j] = bv[j] / (s + EPSV);
}

__global__ __launch_bounds__(256)
void k_rowmv(const float* __restrict__ K, const float* __restrict__ av,
             const float* __restrict__ v, float* __restrict__ u,
             float* __restrict__ du2, const int* __restrict__ flag)
{
    if (*flag) return;
    __shared__ __align__(16) float vl[N];
    for (int j = threadIdx.x; j < N / 4; j += 256)
        ((float4*)vl)[j] = ((const float4*)v)[j];
    __syncthreads();

    const int w    = threadIdx.x >> 6;
    const int lane = threadIdx.x & 63;
    const int i    = blockIdx.x * 4 + w;
    const float4* krow = (const float4*)(K + (size_t)i * N);
    const float4* v4   = (const float4*)vl;

    float acc = 0.f;
    for (int c = lane; c < N / 4; c += 64) {
        float4 k  = krow[c];
        float4 vv = v4[c];
        acc += k.x * vv.x + k.y * vv.y + k.z * vv.z + k.w * vv.w;
    }
    for (int off = 32; off > 0; off >>= 1)
        acc += __shfl_down(acc, off, 64);
    if (lane == 0) {
        float un = av[i] / (acc + EPSV);
        float d  = un - u[i];
        du2[i] = d * d;
        u[i]   = un;
    }
}

__global__ __launch_bounds__(256)
void k_err(const float* __restrict__ du2, int* __restrict__ flag)
{
    if (*flag) return;
    __shared__ float r[4];
    float s = 0.f;
    for (int i = threadIdx.x; i < N; i += 256) s += du2[i];
    for (int off = 32; off > 0; off >>= 1)
        s += __shfl_down(s, off, 64);
    if ((threadIdx.x & 63) == 0) r[threadIdx.x >> 6] = s;
    __syncthreads();
    if (threadIdx.x == 0) {
        float e = sqrtf(r[0] + r[1] + r[2] + r[3]);
        if (e < THRESH) *flag = 1;
    }
}

__global__ __launch_bounds__(256)
void k_final(float* __restrict__ K, const float* __restrict__ u,
             const float* __restrict__ v)
{
    __shared__ __align__(16) float vl[N];
    for (int j = threadIdx.x; j < N / 4; j += 256)
        ((float4*)vl)[j] = ((const float4*)v)[j];
    __syncthreads();

    const int w    = threadIdx.x >> 6;
    const int lane = threadIdx.x & 63;
    const int i    = blockIdx.x * 4 + w;
    const float ui = u[i];
    float4* krow = (float4*)(K + (size_t)i * N);
    const float4* v4 = (const float4*)vl;
    for (int c = lane; c < N / 4; c += 64) {
        float4 k  = krow[c];
        float4 vv = v4[c];
        k.x *= ui * vv.x;
        k.y *= ui * vv.y;
        k.z *= ui * vv.z;
        k.w *= ui * vv.w;
        krow[c] = k;
    }
}

// ===========================================================================
extern "C" void kernel_launch(void* const* d_in, const int* in_sizes, int n_in,
                              void* d_out, int out_size, void* d_ws, size_t ws_size,
                              hipStream_t stream)
{
    const float* cost = (const float*)d_in[0];
    const float* av   = (const float*)d_in[1];
    const float* bv   = (const float*)d_in[2];
    float* K  = (float*)d_out;
    float* ws = (float*)d_ws;

    // Pick coop grid size from a host-side occupancy query (no failed-launch
    // risk inside graph capture). MI355X: 256 CUs.
    int maxb = 0;
    (void)hipOccupancyMaxActiveBlocksPerMultiprocessor(
        &maxb, (const void*)sinkhorn_mega, NTHR, 0);
    int nblk = (maxb >= 4) ? 1024 : (maxb >= 2) ? 512 : 0;

    if (nblk > 0) {
        void* args[] = { (void*)&cost, (void*)&av, (void*)&bv, (void*)&K, (void*)&ws };
        hipError_t rc = hipLaunchCooperativeKernel((const void*)sinkhorn_mega,
                                                   dim3(nblk), dim3(NTHR),
                                                   args, 0, stream);
        if (rc == hipSuccess) return;
    }

    // Fallback: proven round-2 multi-kernel path.
    int*   flag    = (int*)d_ws;
    float* u       = (float*)d_ws + 16;
    float* v       = u + N;
    float* du2     = v + N;
    float* partial = du2 + N;

    k_init<<<2048, 256, 0, stream>>>(cost, K, u, flag);
    for (int it = 0; it < MAX_IT; ++it) {
        k_colmv<<<1024, 256, 0, stream>>>(K, u, partial, flag);
        k_v    <<<  32, 256, 0, stream>>>(partial, bv, v, flag);
        k_rowmv<<<2048, 256, 0, stream>>>(K, av, v, u, du2, flag);
        k_err  <<<   1, 256, 0, stream>>>(du2, flag);
    }
    k_final<<<2048, 256, 0, stream>>>(K, u, v);
}

// Round 5
// 771.989 us; speedup vs baseline: 1.3337x; 1.0412x over previous
//
#include <hip/hip_runtime.h>
#include <hip/hip_fp16.h>
#include <hip/hip_cooperative_groups.h>

namespace cg = cooperative_groups;

constexpr int   N       = 8192;
constexpr float INV_REG = 10.0f;    // 1/REG, REG = 0.1
constexpr float THRESH  = 1e-3f;
constexpr float EPSV    = 1e-8f;
constexpr int   MAX_IT  = 100;
constexpr int   NTHR    = 256;
constexpr int   MAXSLAB = 64;       // ws reservation for partial[slab][N]

// ===========================================================================
// Cooperative mega-kernel. F16=true: iteration matvecs read an fp16 shadow
// of K (half the bytes, fully L3-resident); init/final use fp32 K (d_out).
// ws layout (floats): partial[MAXSLAB][N], u[N], v[N], du2[N], then Kh.
// ===========================================================================
template <bool F16>
__global__ __launch_bounds__(NTHR, 4)
void sinkhorn_mega(const float* __restrict__ cost,
                   const float* __restrict__ av,
                   const float* __restrict__ bv,
                   float* __restrict__ K,          // d_out
                   float* __restrict__ ws,
                   __half* __restrict__ Kh)        // fp16 shadow (F16 only)
{
    cg::grid_group grid = cg::this_grid();

    float* partial = ws;
    float* u       = ws + (size_t)MAXSLAB * N;
    float* v       = u + N;
    float* du2     = v + N;

    const int tid  = threadIdx.x;
    const int bid  = blockIdx.x;
    const int nblk = gridDim.x;
    const int gtid = bid * NTHR + tid;
    const int gsz  = nblk * NTHR;

    const int RS        = nblk >> 4;       // row slabs (16 col-slabs fixed)
    const int rows_slab = N / RS;
    const int rpb       = N / nblk;        // rows per block in row-matvec
    const int per_wave  = rpb >> 2;

    __shared__ __align__(16) float v_lds[N];   // 32 KB
    __shared__ float u_lds[256];
    __shared__ float red[4];
    __shared__ float err_sh;

    // ------------- init: K = exp(-cost/REG) (+ fp16 shadow); u = 1/N -------
    {
        const float4* c4 = (const float4*)cost;
        float4*       k4 = (float4*)K;
        const int tot4 = N * N / 4;
        #pragma unroll 2
        for (int i = gtid; i < tot4; i += gsz) {
            float4 c = c4[i];
            float4 k;
            k.x = __expf(-INV_REG * c.x);
            k.y = __expf(-INV_REG * c.y);
            k.z = __expf(-INV_REG * c.z);
            k.w = __expf(-INV_REG * c.w);
            k4[i] = k;
            if constexpr (F16) {
                __half2 h01 = __floats2half2_rn(k.x, k.y);
                __half2 h23 = __floats2half2_rn(k.z, k.w);
                uint2 raw;
                raw.x = *(const unsigned int*)&h01;
                raw.y = *(const unsigned int*)&h23;
                ((uint2*)Kh)[i] = raw;
            }
        }
        if (gtid < N) u[gtid] = 1.0f / (float)N;
    }
    grid.sync();

    int iter = 0;
    while (true) {
        // ---- A: partial[rs][j] = sum_{r in slab rs} K[r][j] * u[r] ----
        {
            const int rs = bid >> 4;
            const int cs = bid & 15;
            const int r0 = rs * rows_slab;
            const int c0 = cs * 512;
            const int l  = tid & 127;     // covers 4 cols each
            const int h  = tid >> 7;      // row half

            for (int r = tid; r < rows_slab; r += NTHR) u_lds[r] = u[r0 + r];
            __syncthreads();

            float4 acc = make_float4(0.f, 0.f, 0.f, 0.f);
            #pragma unroll 4
            for (int r = h; r < rows_slab; r += 2) {
                float uu = u_lds[r];
                float4 k;
                if constexpr (F16) {
                    uint2 raw = ((const uint2*)(Kh + (size_t)(r0 + r) * N))[(c0 >> 2) + l];
                    float2 f01 = __half22float2(*(const __half2*)&raw.x);
                    float2 f23 = __half22float2(*(const __half2*)&raw.y);
                    k.x = f01.x; k.y = f01.y; k.z = f23.x; k.w = f23.y;
                } else {
                    k = ((const float4*)(K + (size_t)(r0 + r) * N))[(c0 >> 2) + l];
                }
                acc.x += k.x * uu;
                acc.y += k.y * uu;
                acc.z += k.z * uu;
                acc.w += k.w * uu;
            }
            if (h == 1) ((float4*)v_lds)[l] = acc;
            __syncthreads();
            if (h == 0) {
                float4 o = ((float4*)v_lds)[l];
                acc.x += o.x; acc.y += o.y; acc.z += o.z; acc.w += o.w;
                ((float4*)(partial + (size_t)rs * N + c0))[l] = acc;
            }
            __syncthreads();   // v_lds scratch free before next use
        }
        grid.sync();

        // ---- A2: v[j] = b[j] / (sum_s partial[s][j] + eps) ----
        if (gtid < N) {
            float s = 0.f;
            for (int sl = 0; sl < RS; ++sl) s += partial[(size_t)sl * N + gtid];
            v[gtid] = bv[gtid] / (s + EPSV);
        }
        grid.sync();

        // ---- B: u[i] = a[i] / (K[i,:].v + eps); du2 ----
        {
            for (int j = tid; j < N / 4; j += NTHR)
                ((float4*)v_lds)[j] = ((const float4*)v)[j];
            __syncthreads();

            const int w    = tid >> 6;
            const int lane = tid & 63;
            const float4* v4 = (const float4*)v_lds;
            for (int rr = 0; rr < per_wave; ++rr) {
                const int i = bid * rpb + w * per_wave + rr;
                float acc = 0.f;
                if constexpr (F16) {
                    const uint4* krow = (const uint4*)(Kh + (size_t)i * N);
                    #pragma unroll 4
                    for (int c = lane; c < N / 8; c += 64) {
                        uint4 raw = krow[c];
                        float2 f0 = __half22float2(*(const __half2*)&raw.x);
                        float2 f1 = __half22float2(*(const __half2*)&raw.y);
                        float2 f2 = __half22float2(*(const __half2*)&raw.z);
                        float2 f3 = __half22float2(*(const __half2*)&raw.w);
                        float4 va = v4[2 * c];
                        float4 vb = v4[2 * c + 1];
                        acc += f0.x * va.x + f0.y * va.y + f1.x * va.z + f1.y * va.w;
                        acc += f2.x * vb.x + f2.y * vb.y + f3.x * vb.z + f3.y * vb.w;
                    }
                } else {
                    const float4* krow = (const float4*)(K + (size_t)i * N);
                    #pragma unroll 4
                    for (int c = lane; c < N / 4; c += 64) {
                        float4 k  = krow[c];
                        float4 vv = v4[c];
                        acc += k.x * vv.x + k.y * vv.y + k.z * vv.z + k.w * vv.w;
                    }
                }
                for (int off = 32; off > 0; off >>= 1)
                    acc += __shfl_down(acc, off, 64);
                if (lane == 0) {
                    float un = av[i] / (acc + EPSV);
                    float d  = un - u[i];
                    du2[i] = d * d;
                    u[i]   = un;
                }
            }
        }
        grid.sync();

        // ---- C: every block redundantly reduces du2 (identical fp order) ----
        {
            float s = 0.f;
            for (int i = tid; i < N; i += NTHR) s += du2[i];
            for (int off = 32; off > 0; off >>= 1)
                s += __shfl_down(s, off, 64);
            if ((tid & 63) == 0) red[tid >> 6] = s;
            __syncthreads();
            if (tid == 0) err_sh = sqrtf(red[0] + red[1] + red[2] + red[3]);
            __syncthreads();
            float err = err_sh;
            ++iter;
            if (iter >= MAX_IT || err < THRESH) break;
        }
    }

    // ---- final: K[i][j] *= u[i]*v[j] (fp32 K); v_lds still holds v ----
    {
        const int w    = tid >> 6;
        const int lane = tid & 63;
        const float4* v4 = (const float4*)v_lds;
        for (int rr = 0; rr < per_wave; ++rr) {
            const int i = bid * rpb + w * per_wave + rr;
            const float ui = u[i];
            float4* krow = (float4*)(K + (size_t)i * N);
            #pragma unroll 4
            for (int c = lane; c < N / 4; c += 64) {
                float4 k  = krow[c];
                float4 vv = v4[c];
                k.x *= ui * vv.x;
                k.y *= ui * vv.y;
                k.z *= ui * vv.z;
                k.w *= ui * vv.w;
                krow[c] = k;
            }
        }
    }
}

// ===========================================================================
// Fallback path (round-2 proven multi-kernel) — only if coop launch impossible
// ===========================================================================
constexpr int NSLAB_F = 64;

__global__ __launch_bounds__(256)
void k_init(const float* __restrict__ cost, float* __restrict__ K,
            float* __restrict__ u, int* __restrict__ flag)
{
    const int gtid = blockIdx.x * 256 + threadIdx.x;
    const int gsz  = gridDim.x * 256;
    const float4* c4 = (const float4*)cost;
    float4*       k4 = (float4*)K;
    const int tot4 = N * N / 4;
    for (int i = gtid; i < tot4; i += gsz) {
        float4 c = c4[i];
        float4 k;
        k.x = __expf(-INV_REG * c.x);
        k.y = __expf(-INV_REG * c.y);
        k.z = __expf(-INV_REG * c.z);
        k.w = __expf(-INV_REG * c.w);
        k4[i] = k;
    }
    if (gtid < N) u[gtid] = 1.0f / (float)N;
    if (gtid == 0) *flag = 0;
}

__global__ __launch_bounds__(256)
void k_colmv(const float* __restrict__ K, const float* __restrict__ u,
             float* __restrict__ partial, const int* __restrict__ flag)
{
    if (*flag) return;
    __shared__ float  uh[128];
    __shared__ __align__(16) float4 accs[128];

    const int rs = blockIdx.x >> 4;
    const int cs = blockIdx.x & 15;
    const int r0 = rs * 128;
    const int c0 = cs * 512;
    const int l  = threadIdx.x & 127;
    const int h  = threadIdx.x >> 7;

    if (threadIdx.x < 128) uh[threadIdx.x] = u[r0 + threadIdx.x];
    __syncthreads();

    float4 acc = make_float4(0.f, 0.f, 0.f, 0.f);
    for (int r = h; r < 128; r += 2) {
        float4 k = ((const float4*)(K + (size_t)(r0 + r) * N))[(c0 >> 2) + l];
        float uu = uh[r];
        acc.x += k.x * uu;
        acc.y += k.y * uu;
        acc.z += k.z * uu;
        acc.w += k.w * uu;
    }
    if (h == 1) accs[l] = acc;
    __syncthreads();
    if (h == 0) {
        float4 o = accs[l];
        acc.x += o.x; acc.y += o.y; acc.z += o.z; acc.w += o.w;
        ((float4*)(partial + (size_t)rs * N + c0))[l] = acc;
    }
}

__global__ __launch_bounds__(256)
void k_v(const float* __restrict__ partial, const float* __restrict__ bv,
         float* __restrict__ v, const int* __restrict__ flag)
{
    if (*flag) return;
    const int j = blockIdx.x * 256 + threadIdx.x;
    float s = 0.f;
    for (int sl = 0; sl < NSLAB_F; ++sl) s += partial[(size_t)sl * N + j];
    v[j] = bv[j] / (s + EPSV);
}

__global__ __launch_bounds__(256)
void k_rowmv(const float* __restrict__ K, const float* __restrict__ av,
             const float* __restrict__ v, float* __restrict__ u,
             float* __restrict__ du2, const int* __restrict__ flag)
{
    if (*flag) return;
    __shared__ __align__(16) float vl[N];
    for (int j = threadIdx.x; j < N / 4; j += 256)
        ((float4*)vl)[j] = ((const float4*)v)[j];
    __syncthreads();

    const int w    = threadIdx.x >> 6;
    const int lane = threadIdx.x & 63;
    const int i    = blockIdx.x * 4 + w;
    const float4* krow = (const float4*)(K + (size_t)i * N);
    const float4* v4   = (const float4*)vl;

    float acc = 0.f;
    for (int c = lane; c < N / 4; c += 64) {
        float4 k  = krow[c];
        float4 vv = v4[c];
        acc += k.x * vv.x + k.y * vv.y + k.z * vv.z + k.w * vv.w;
    }
    for (int off = 32; off > 0; off >>= 1)
        acc += __shfl_down(acc, off, 64);
    if (lane == 0) {
        float un = av[i] / (acc + EPSV);
        float d  = un - u[i];
        du2[i] = d * d;
        u[i]   = un;
    }
}

__global__ __launch_bounds__(256)
void k_err(const float* __restrict__ du2, int* __restrict__ flag)
{
    if (*flag) return;
    __shared__ float r[4];
    float s = 0.f;
    for (int i = threadIdx.x; i < N; i += 256) s += du2[i];
    for (int off = 32; off > 0; off >>= 1)
        s += __shfl_down(s, off, 64);
    if ((threadIdx.x & 63) == 0) r[threadIdx.x >> 6] = s;
    __syncthreads();
    if (threadIdx.x == 0) {
        float e = sqrtf(r[0] + r[1] + r[2] + r[3]);
        if (e < THRESH) *flag = 1;
    }
}

__global__ __launch_bounds__(256)
void k_final(float* __restrict__ K, const float* __restrict__ u,
             const float* __restrict__ v)
{
    __shared__ __align__(16) float vl[N];
    for (int j = threadIdx.x; j < N / 4; j += 256)
        ((float4*)vl)[j] = ((const float4*)v)[j];
    __syncthreads();

    const int w    = threadIdx.x >> 6;
    const int lane = threadIdx.x & 63;
    const int i    = blockIdx.x * 4 + w;
    const float ui = u[i];
    float4* krow = (float4*)(K + (size_t)i * N);
    const float4* v4 = (const float4*)vl;
    for (int c = lane; c < N / 4; c += 64) {
        float4 k  = krow[c];
        float4 vv = v4[c];
        k.x *= ui * vv.x;
        k.y *= ui * vv.y;
        k.z *= ui * vv.z;
        k.w *= ui * vv.w;
        krow[c] = k;
    }
}

// ===========================================================================
extern "C" void kernel_launch(void* const* d_in, const int* in_sizes, int n_in,
                              void* d_out, int out_size, void* d_ws, size_t ws_size,
                              hipStream_t stream)
{
    const float* cost = (const float*)d_in[0];
    const float* av   = (const float*)d_in[1];
    const float* bv   = (const float*)d_in[2];
    float* K  = (float*)d_out;
    float* ws = (float*)d_ws;

    // ws: partial[64*N] + u,v,du2 (3N) floats, then fp16 shadow Kh[N*N].
    const size_t head_floats = (size_t)(MAXSLAB + 3) * N;
    const size_t need_f16    = head_floats * 4 + (size_t)N * N * 2;
    const bool   use_f16     = (ws_size >= need_f16);
    __half* Kh = (__half*)(ws + head_floats);

    const void* fn = use_f16 ? (const void*)sinkhorn_mega<true>
                             : (const void*)sinkhorn_mega<false>;

    int maxb = 0;
    (void)hipOccupancyMaxActiveBlocksPerMultiprocessor(&maxb, fn, NTHR, 0);
    int nblk = (maxb >= 4) ? 1024 : (maxb >= 2) ? 512 : 0;

    if (nblk > 0) {
        void* args[] = { (void*)&cost, (void*)&av, (void*)&bv,
                         (void*)&K, (void*)&ws, (void*)&Kh };
        hipError_t rc = hipLaunchCooperativeKernel(fn, dim3(nblk), dim3(NTHR),
                                                   args, 0, stream);
        if (rc == hipSuccess) return;
    }

    // Fallback: proven round-2 multi-kernel path.
    int*   flag    = (int*)d_ws;
    float* u       = (float*)d_ws + 16;
    float* v       = u + N;
    float* du2     = v + N;
    float* partial = du2 + N;

    k_init<<<2048, 256, 0, stream>>>(cost, K, u, flag);
    for (int it = 0; it < MAX_IT; ++it) {
        k_colmv<<<1024, 256, 0, stream>>>(K, u, partial, flag);
        k_v    <<<  32, 256, 0, stream>>>(partial, bv, v, flag);
        k_rowmv<<<2048, 256, 0, stream>>>(K, av, v, u, du2, flag);
        k_err  <<<   1, 256, 0, stream>>>(du2, flag);
    }
    k_final<<<2048, 256, 0, stream>>>(K, u, v);
}

// Round 7
// 718.200 us; speedup vs baseline: 1.4336x; 1.0749x over previous
//
#include <hip/hip_runtime.h>
#include <hip/hip_fp16.h>
#include <hip/hip_cooperative_groups.h>

namespace cg = cooperative_groups;

typedef float  fx4 __attribute__((ext_vector_type(4)));   // clang vector: OK for nontemporal builtins

constexpr int   N       = 8192;
constexpr float INV_REG = 10.0f;    // 1/REG, REG = 0.1
constexpr float THRESH  = 1e-3f;
constexpr float EPSV    = 1e-8f;
constexpr int   MAX_IT  = 100;
constexpr int   NTHR    = 256;
constexpr int   MAXSLAB = 64;       // ws reservation for partial[slab][N]

// 8-halfs dot 8-floats -> acc
__device__ __forceinline__ void dot8(const uint4& raw, const float4& va,
                                     const float4& vb, float& acc)
{
    float2 f0 = __half22float2(*(const __half2*)&raw.x);
    float2 f1 = __half22float2(*(const __half2*)&raw.y);
    float2 f2 = __half22float2(*(const __half2*)&raw.z);
    float2 f3 = __half22float2(*(const __half2*)&raw.w);
    acc += f0.x * va.x + f0.y * va.y + f1.x * va.z + f1.y * va.w
         + f2.x * vb.x + f2.y * vb.y + f3.x * vb.z + f3.y * vb.w;
}

// ===========================================================================
// Cooperative mega-kernel. Iteration matvecs read an fp16 shadow Kh (L3-
// resident, 128 MB). fp32 K is never materialized: the final pass recomputes
// exp(-cost/REG) (identical __expf as init) and writes u_i*K_ij*v_j to out.
// ws layout (floats): partial[MAXSLAB][N], u[N], v[N], du2[N], then Kh (fp16).
// Grid-size agnostic for nblk in {512, 1024} (16 col-slabs fixed).
// ===========================================================================
__global__ __launch_bounds__(NTHR, 4)
void sinkhorn_mega(const float* __restrict__ cost,
                   const float* __restrict__ av,
                   const float* __restrict__ bv,
                   float* __restrict__ out,        // d_out: final plan only
                   float* __restrict__ ws,
                   __half* __restrict__ Kh)        // fp16 shadow of K
{
    cg::grid_group grid = cg::this_grid();

    float* partial = ws;
    float* u       = ws + (size_t)MAXSLAB * N;
    float* v       = u + N;
    float* du2     = v + N;

    const int tid  = threadIdx.x;
    const int bid  = blockIdx.x;
    const int nblk = gridDim.x;
    const int gtid = bid * NTHR + tid;
    const int gsz  = nblk * NTHR;

    const int RS        = nblk >> 4;       // row slabs (16 col-slabs fixed)
    const int rows_slab = N / RS;          // 128 @1024 blk, 256 @512 blk
    const int rpb       = N / nblk;        // rows per block in row-matvec
    const int per_wave  = rpb >> 2;        // rows per wave (2 @1024)

    const int w    = tid >> 6;
    const int lane = tid & 63;

    __shared__ __align__(16) float v_lds[N];   // 32 KB (v; also A's scratch)
    __shared__ float u_lds[256];
    __shared__ float red[4];
    __shared__ float err_sh;

    // ---- init: Kh = fp16(exp(-cost/REG)); u = 1/N. cost read non-temporal
    //      so it doesn't evict the Kh lines we're about to live out of L3.
    {
        const fx4* c4 = (const fx4*)cost;
        const int tot4 = N * N / 4;
        #pragma unroll 2
        for (int i = gtid; i < tot4; i += gsz) {
            fx4 c = __builtin_nontemporal_load(&c4[i]);
            __half2 h01 = __floats2half2_rn(__expf(-INV_REG * c.x),
                                            __expf(-INV_REG * c.y));
            __half2 h23 = __floats2half2_rn(__expf(-INV_REG * c.z),
                                            __expf(-INV_REG * c.w));
            uint2 raw;
            raw.x = *(const unsigned int*)&h01;
            raw.y = *(const unsigned int*)&h23;
            ((uint2*)Kh)[i] = raw;
        }
        if (gtid < N) u[gtid] = 1.0f / (float)N;
    }
    grid.sync();

    int iter = 0;
    while (true) {
        // ---- A: partial[rs][j] = sum_{r in slab} Kh[r][j] * u[r] ----
        // wave-per-row: lane covers 8 cols (one uint4), rows step 4.
        {
            const int rs = bid >> 4;
            const int cs = bid & 15;
            const int r0 = rs * rows_slab;
            const int c0 = cs * 512;

            for (int r = tid; r < rows_slab; r += NTHR) u_lds[r] = u[r0 + r];
            __syncthreads();

            float a0 = 0.f, a1 = 0.f, a2 = 0.f, a3 = 0.f;
            float a4 = 0.f, a5 = 0.f, a6 = 0.f, a7 = 0.f;
            const __half* kbase = Kh + (size_t)r0 * N + c0 + lane * 8;
            #pragma unroll 8
            for (int r = w; r < rows_slab; r += 4) {
                uint4 raw = *(const uint4*)(kbase + (size_t)r * N);
                float uu  = u_lds[r];
                float2 f0 = __half22float2(*(const __half2*)&raw.x);
                float2 f1 = __half22float2(*(const __half2*)&raw.y);
                float2 f2 = __half22float2(*(const __half2*)&raw.z);
                float2 f3 = __half22float2(*(const __half2*)&raw.w);
                a0 += f0.x * uu; a1 += f0.y * uu;
                a2 += f1.x * uu; a3 += f1.y * uu;
                a4 += f2.x * uu; a5 += f2.y * uu;
                a6 += f3.x * uu; a7 += f3.y * uu;
            }
            // cross-wave reduce via v_lds scratch (4 x 512 floats = 8 KB)
            float4* scr = (float4*)v_lds;
            scr[w * 128 + lane * 2]     = make_float4(a0, a1, a2, a3);
            scr[w * 128 + lane * 2 + 1] = make_float4(a4, a5, a6, a7);
            __syncthreads();
            {
                const int idx = tid * 2;     // 0..510
                float sx = 0.f, sy = 0.f;
                #pragma unroll
                for (int ww = 0; ww < 4; ++ww) {
                    sx += v_lds[ww * 512 + idx];
                    sy += v_lds[ww * 512 + idx + 1];
                }
                ((float2*)(partial + (size_t)rs * N + c0))[tid] =
                    make_float2(sx, sy);
            }
            __syncthreads();   // v_lds scratch free
        }
        grid.sync();

        // ---- A2: v[j] = b[j] / (sum_s partial[s][j] + eps) ----
        if (gtid < N) {
            float s = 0.f;
            for (int sl = 0; sl < RS; ++sl) s += partial[(size_t)sl * N + gtid];
            v[gtid] = bv[gtid] / (s + EPSV);
        }
        grid.sync();

        // ---- B: u[i] = a[i] / (Kh[i,:].v + eps); du2. 2 rows/wave interleaved
        {
            for (int j = tid; j < N / 4; j += NTHR)
                ((float4*)v_lds)[j] = ((const float4*)v)[j];
            __syncthreads();

            const float4* v4 = (const float4*)v_lds;
            for (int pp = 0; pp < per_wave; pp += 2) {
                const int i0 = bid * rpb + w * per_wave + pp;
                const int i1 = i0 + 1;
                const uint4* kr0 = (const uint4*)(Kh + (size_t)i0 * N);
                const uint4* kr1 = (const uint4*)(Kh + (size_t)i1 * N);
                float acc0 = 0.f, acc1 = 0.f;
                #pragma unroll 4
                for (int c = lane; c < N / 8; c += 64) {
                    uint4 r0v = kr0[c];
                    uint4 r1v = kr1[c];
                    float4 va = v4[2 * c];
                    float4 vb = v4[2 * c + 1];
                    dot8(r0v, va, vb, acc0);
                    dot8(r1v, va, vb, acc1);
                }
                for (int off = 32; off > 0; off >>= 1) {
                    acc0 += __shfl_down(acc0, off, 64);
                    acc1 += __shfl_down(acc1, off, 64);
                }
                if (lane == 0) {
                    float un0 = av[i0] / (acc0 + EPSV);
                    float un1 = av[i1] / (acc1 + EPSV);
                    float d0  = un0 - u[i0];
                    float d1  = un1 - u[i1];
                    du2[i0] = d0 * d0;
                    du2[i1] = d1 * d1;
                    u[i0]   = un0;
                    u[i1]   = un1;
                }
            }
        }
        grid.sync();

        // ---- C: every block redundantly reduces du2 (identical fp order) ----
        {
            float s = 0.f;
            for (int i = tid; i < N; i += NTHR) s += du2[i];
            for (int off = 32; off > 0; off >>= 1)
                s += __shfl_down(s, off, 64);
            if ((tid & 63) == 0) red[tid >> 6] = s;
            __syncthreads();
            if (tid == 0) err_sh = sqrtf(red[0] + red[1] + red[2] + red[3]);
            __syncthreads();
            float err = err_sh;
            ++iter;
            if (iter >= MAX_IT || err < THRESH) break;
        }
    }

    // ---- final: out[i][j] = u_i * exp(-10*c_ij) * v_j. v_lds holds v. ----
    {
        const float4* v4 = (const float4*)v_lds;
        for (int pp = 0; pp < per_wave; ++pp) {
            const int i = bid * rpb + w * per_wave + pp;
            const float ui = u[i];
            const fx4* crow = (const fx4*)(cost + (size_t)i * N);
            fx4*       orow = (fx4*)(out + (size_t)i * N);
            #pragma unroll 4
            for (int c = lane; c < N / 4; c += 64) {
                fx4 cc = __builtin_nontemporal_load(&crow[c]);
                float4 vv = v4[c];
                fx4 o;
                o.x = ui * __expf(-INV_REG * cc.x) * vv.x;
                o.y = ui * __expf(-INV_REG * cc.y) * vv.y;
                o.z = ui * __expf(-INV_REG * cc.z) * vv.z;
                o.w = ui * __expf(-INV_REG * cc.w) * vv.w;
                __builtin_nontemporal_store(o, &orow[c]);
            }
        }
    }
}

// ===========================================================================
// Fallback path (round-2 proven multi-kernel) — only if coop launch impossible
// ===========================================================================
constexpr int NSLAB_F = 64;

__global__ __launch_bounds__(256)
void k_init(const float* __restrict__ cost, float* __restrict__ K,
            float* __restrict__ u, int* __restrict__ flag)
{
    const int gtid = blockIdx.x * 256 + threadIdx.x;
    const int gsz  = gridDim.x * 256;
    const float4* c4 = (const float4*)cost;
    float4*       k4 = (float4*)K;
    const int tot4 = N * N / 4;
    for (int i = gtid; i < tot4; i += gsz) {
        float4 c = c4[i];
        float4 k;
        k.x = __expf(-INV_REG * c.x);
        k.y = __expf(-INV_REG * c.y);
        k.z = __expf(-INV_REG * c.z);
        k.w = __expf(-INV_REG * c.w);
        k4[i] = k;
    }
    if (gtid < N) u[gtid] = 1.0f / (float)N;
    if (gtid == 0) *flag = 0;
}

__global__ __launch_bounds__(256)
void k_colmv(const float* __restrict__ K, const float* __restrict__ u,
             float* __restrict__ partial, const int* __restrict__ flag)
{
    if (*flag) return;
    __shared__ float  uh[128];
    __shared__ __align__(16) float4 accs[128];

    const int rs = blockIdx.x >> 4;
    const int cs = blockIdx.x & 15;
    const int r0 = rs * 128;
    const int c0 = cs * 512;
    const int l  = threadIdx.x & 127;
    const int h  = threadIdx.x >> 7;

    if (threadIdx.x < 128) uh[threadIdx.x] = u[r0 + threadIdx.x];
    __syncthreads();

    float4 acc = make_float4(0.f, 0.f, 0.f, 0.f);
    for (int r = h; r < 128; r += 2) {
        float4 k = ((const float4*)(K + (size_t)(r0 + r) * N))[(c0 >> 2) + l];
        float uu = uh[r];
        acc.x += k.x * uu;
        acc.y += k.y * uu;
        acc.z += k.z * uu;
        acc.w += k.w * uu;
    }
    if (h == 1) accs[l] = acc;
    __syncthreads();
    if (h == 0) {
        float4 o = accs[l];
        acc.x += o.x; acc.y += o.y; acc.z += o.z; acc.w += o.w;
        ((float4*)(partial + (size_t)rs * N + c0))[l] = acc;
    }
}

__global__ __launch_bounds__(256)
void k_v(const float* __restrict__ partial, const float* __restrict__ bv,
         float* __restrict__ v, const int* __restrict__ flag)
{
    if (*flag) return;
    const int j = blockIdx.x * 256 + threadIdx.x;
    float s = 0.f;
    for (int sl = 0; sl < NSLAB_F; ++sl) s += partial[(size_t)sl * N + j];
    v[j] = bv[j] / (s + EPSV);
}

__global__ __launch_bounds__(256)
void k_rowmv(const float* __restrict__ K, const float* __restrict__ av,
             const float* __restrict__ v, float* __restrict__ u,
             float* __restrict__ du2, const int* __restrict__ flag)
{
    if (*flag) return;
    __shared__ __align__(16) float vl[N];
    for (int j = threadIdx.x; j < N / 4; j += 256)
        ((float4*)vl)[j] = ((const float4*)v)[j];
    __syncthreads();

    const int w    = threadIdx.x >> 6;
    const int lane = threadIdx.x & 63;
    const int i    = blockIdx.x * 4 + w;
    const float4* krow = (const float4*)(K + (size_t)i * N);
    const float4* v4   = (const float4*)vl;

    float acc = 0.f;
    for (int c = lane; c < N / 4; c += 64) {
        float4 k  = krow[c];
        float4 vv = v4[c];
        acc += k.x * vv.x + k.y * vv.y + k.z * vv.z + k.w * vv.w;
    }
    for (int off = 32; off > 0; off >>= 1)
        acc += __shfl_down(acc, off, 64);
    if (lane == 0) {
        float un = av[i] / (acc + EPSV);
        float d  = un - u[i];
        du2[i] = d * d;
        u[i]   = un;
    }
}

__global__ __launch_bounds__(256)
void k_err(const float* __restrict__ du2, int* __restrict__ flag)
{
    if (*flag) return;
    __shared__ float r[4];
    float s = 0.f;
    for (int i = threadIdx.x; i < N; i += 256) s += du2[i];
    for (int off = 32; off > 0; off >>= 1)
        s += __shfl_down(s, off, 64);
    if ((threadIdx.x & 63) == 0) r[threadIdx.x >> 6] = s;
    __syncthreads();
    if (threadIdx.x == 0) {
        float e = sqrtf(r[0] + r[1] + r[2] + r[3]);
        if (e < THRESH) *flag = 1;
    }
}

__global__ __launch_bounds__(256)
void k_final(float* __restrict__ K, const float* __restrict__ u,
             const float* __restrict__ v)
{
    __shared__ __align__(16) float vl[N];
    for (int j = threadIdx.x; j < N / 4; j += 256)
        ((float4*)vl)[j] = ((const float4*)v)[j];
    __syncthreads();

    const int w    = threadIdx.x >> 6;
    const int lane = threadIdx.x & 63;
    const int i    = blockIdx.x * 4 + w;
    const float ui = u[i];
    float4* krow = (float4*)(K + (size_t)i * N);
    const float4* v4 = (const float4*)vl;
    for (int c = lane; c < N / 4; c += 64) {
        float4 k  = krow[c];
        float4 vv = v4[c];
        k.x *= ui * vv.x;
        k.y *= ui * vv.y;
        k.z *= ui * vv.z;
        k.w *= ui * vv.w;
        krow[c] = k;
    }
}

// ===========================================================================
extern "C" void kernel_launch(void* const* d_in, const int* in_sizes, int n_in,
                              void* d_out, int out_size, void* d_ws, size_t ws_size,
                              hipStream_t stream)
{
    const float* cost = (const float*)d_in[0];
    const float* av   = (const float*)d_in[1];
    const float* bv   = (const float*)d_in[2];
    float* out = (float*)d_out;
    float* ws  = (float*)d_ws;

    // ws: partial[64*N] + u,v,du2 (3N) floats, then fp16 shadow Kh[N*N].
    const size_t head_floats = (size_t)(MAXSLAB + 3) * N;
    const size_t need_f16    = head_floats * 4 + (size_t)N * N * 2;
    __half* Kh = (__half*)(ws + head_floats);

    if (ws_size >= need_f16) {
        int maxb = 0;
        (void)hipOccupancyMaxActiveBlocksPerMultiprocessor(
            &maxb, (const void*)sinkhorn_mega, NTHR, 0);
        int nblk = (maxb >= 4) ? 1024 : (maxb >= 2) ? 512 : 0;
        if (nblk > 0) {
            void* args[] = { (void*)&cost, (void*)&av, (void*)&bv,
                             (void*)&out, (void*)&ws, (void*)&Kh };
            hipError_t rc = hipLaunchCooperativeKernel(
                (const void*)sinkhorn_mega, dim3(nblk), dim3(NTHR),
                args, 0, stream);
            if (rc == hipSuccess) return;
        }
    }

    // Fallback: proven round-2 multi-kernel path (fp32 K in d_out).
    int*   flag    = (int*)d_ws;
    float* u       = (float*)d_ws + 16;
    float* v       = u + N;
    float* du2     = v + N;
    float* partial = du2 + N;

    k_init<<<2048, 256, 0, stream>>>(cost, out, u, flag);
    for (int it = 0; it < MAX_IT; ++it) {
        k_colmv<<<1024, 256, 0, stream>>>(out, u, partial, flag);
        k_v    <<<  32, 256, 0, stream>>>(partial, bv, v, flag);
        k_rowmv<<<2048, 256, 0, stream>>>(out, av, v, u, du2, flag);
        k_err  <<<   1, 256, 0, stream>>>(du2, flag);
    }
    k_final<<<2048, 256, 0, stream>>>(out, u, v);
}